// Round 9
// baseline (775.159 us; speedup 1.0000x reference)
//
#include <hip/hip_runtime.h>
#include <cstdint>
#include <cstddef>

#define BIN_TILE    4096
#define BIN_THREADS 512

typedef __attribute__((ext_vector_type(8))) short short8;
typedef __attribute__((ext_vector_type(4))) float f32x4;

static __device__ __forceinline__ unsigned f2bf_rne(float f) {
    unsigned u = __float_as_uint(f);
    return (u + 0x7FFFu + ((u >> 16) & 1u)) >> 16;
}
static __device__ __forceinline__ float bf2f(unsigned h) {
    return __uint_as_float(h << 16);
}

// ---------------- x0 = bf16(emb[node_ids]) ----------------
__global__ void gather_x0bf_k(const int* __restrict__ nid, const float* __restrict__ emb,
                              unsigned* __restrict__ xw, int N) {
    int i = blockIdx.x * blockDim.x + threadIdx.x;
    int n = i >> 6;
    if (n >= N) return;
    int l = i & 63;
    int s = nid[n];
    float2 v = *reinterpret_cast<const float2*>(emb + (size_t)s * 128 + 2 * l);
    xw[(size_t)n * 64 + l] = f2bf_rne(v.x) | (f2bf_rne(v.y) << 16);
}

// ---------------- global bucket histogram (LDS-staged merge) ----------------
__global__ void ghist_k(const int* __restrict__ erow, int* __restrict__ gcnt, int E, int nbkt) {
    extern __shared__ int lcnt[];
    for (int i = threadIdx.x; i < nbkt; i += blockDim.x) lcnt[i] = 0;
    __syncthreads();
    for (int e = blockIdx.x * blockDim.x + threadIdx.x; e < E; e += gridDim.x * blockDim.x)
        atomicAdd(&lcnt[erow[e] >> 8], 1);
    __syncthreads();
    for (int i = threadIdx.x; i < nbkt; i += blockDim.x)
        if (lcnt[i]) atomicAdd(&gcnt[i], lcnt[i]);
}

// ---------------- single-block exclusive scan over nbkt (<=1024) buckets ----------------
__global__ void scanB_k(const int* __restrict__ gcnt, int* __restrict__ fstart,
                        int* __restrict__ gcur, int nbkt) {
    __shared__ int ts[256];
    int tid = threadIdx.x;
    int idx = tid * 4;
    int v0 = (idx + 0 < nbkt) ? gcnt[idx + 0] : 0;
    int v1 = (idx + 1 < nbkt) ? gcnt[idx + 1] : 0;
    int v2 = (idx + 2 < nbkt) ? gcnt[idx + 2] : 0;
    int v3 = (idx + 3 < nbkt) ? gcnt[idx + 3] : 0;
    int local = v0 + v1 + v2 + v3;
    ts[tid] = local;
    __syncthreads();
    for (int off = 1; off < 256; off <<= 1) {
        int t = (tid >= off) ? ts[tid - off] : 0;
        __syncthreads();
        ts[tid] += t;
        __syncthreads();
    }
    int run = ts[tid] - local;
    if (idx + 0 < nbkt) { fstart[idx + 0] = run; gcur[idx + 0] = run; } run += v0;
    if (idx + 1 < nbkt) { fstart[idx + 1] = run; gcur[idx + 1] = run; } run += v1;
    if (idx + 2 < nbkt) { fstart[idx + 2] = run; gcur[idx + 2] = run; } run += v2;
    if (idx + 3 < nbkt) { fstart[idx + 3] = run; gcur[idx + 3] = run; }
    if (tid == 255) fstart[nbkt] = ts[255];
}

// ---------------- LDS-staged binning: tile -> bucket-grouped runs, coalesced flush ----------------
__global__ __launch_bounds__(BIN_THREADS) void bin_k(const int* __restrict__ erow,
                                                     const int* __restrict__ ecol,
                                                     const float* __restrict__ eval,
                                                     int* __restrict__ gcur,
                                                     uint2* __restrict__ cv1, int E, int nbkt) {
    extern __shared__ char smem[];
    uint2*    stg  = (uint2*)smem;                          // BIN_TILE*8
    unsigned* gdst = (unsigned*)(smem + BIN_TILE * 8);      // BIN_TILE*4
    int* cnt   = (int*)(smem + BIN_TILE * 12);              // nbkt
    int* off   = cnt + nbkt;                                // nbkt
    int* gbase = off + nbkt;                                // nbkt
    int* cur   = gbase + nbkt;                              // nbkt
    __shared__ int ts[BIN_THREADS];

    int tid = threadIdx.x;
    int t0 = blockIdx.x * BIN_TILE;
    int tn = min(BIN_TILE, E - t0);

    for (int i = tid; i < nbkt; i += BIN_THREADS) cnt[i] = 0;
    __syncthreads();
    for (int i = tid; i < tn; i += BIN_THREADS)
        atomicAdd(&cnt[erow[t0 + i] >> 8], 1);
    __syncthreads();
    {   // exclusive scan of cnt -> off (2 items/thread)
        int idx = tid * 2;
        int a = (idx < nbkt) ? cnt[idx] : 0;
        int b = (idx + 1 < nbkt) ? cnt[idx + 1] : 0;
        int local = a + b;
        ts[tid] = local;
        __syncthreads();
        for (int o = 1; o < BIN_THREADS; o <<= 1) {
            int t = (tid >= o) ? ts[tid - o] : 0;
            __syncthreads();
            ts[tid] += t;
            __syncthreads();
        }
        int run = ts[tid] - local;
        if (idx < nbkt) off[idx] = run;
        if (idx + 1 < nbkt) off[idx + 1] = run + a;
    }
    __syncthreads();
    for (int b = tid; b < nbkt; b += BIN_THREADS) {
        int c = cnt[b];
        gbase[b] = c ? atomicAdd(&gcur[b], c) : 0;
        cur[b] = 0;
    }
    __syncthreads();
    for (int i = tid; i < tn; i += BIN_THREADS) {
        int r = erow[t0 + i];
        int b = r >> 8;
        unsigned meta = ((unsigned)(r & 255) << 18) | (unsigned)ecol[t0 + i];
        int s = off[b] + atomicAdd(&cur[b], 1);
        stg[s] = make_uint2(meta, __float_as_uint(eval[t0 + i]));
        gdst[s] = (unsigned)(gbase[b] + (s - off[b]));
    }
    __syncthreads();
    for (int s = tid; s < tn; s += BIN_THREADS)
        cv1[gdst[s]] = stg[s];
}

// ---------------- per-bucket sort by (row, colbin): locality-ordered row-sorted cv2 + rs[] ----------------
// key = (row_local<<6) | (col>>12): rows contiguous (spmm needs that); within a row,
// edges ascend in ~1MB column bins so co-resident waves share an L2-sized column window.
__global__ __launch_bounds__(256) void rowsort_k(const int* __restrict__ fstart,
                                                 const uint2* __restrict__ cv1,
                                                 uint2* __restrict__ cv2,
                                                 int* __restrict__ rs, int N, int E) {
    __shared__ int sc[16384];       // 256 rows x 64 col bins
    __shared__ int ts[256];
    int fb = blockIdx.x;
    int base = fb << 8;
    int tid = threadIdx.x;
    for (int i = tid; i < 16384; i += 256) sc[i] = 0;
    __syncthreads();
    int fs = fstart[fb], fe = fstart[fb + 1];
    for (int i = fs + tid; i < fe; i += 256) {
        unsigned m = cv1[i].x;
        int key = (int)((m >> 18) << 6) | (int)((m & 0x3FFFFu) >> 12);
        atomicAdd(&sc[key], 1);
    }
    __syncthreads();
    // exclusive scan over 16384 (64 per thread)
    int t0 = tid << 6;
    int local = 0;
#pragma unroll 8
    for (int j = 0; j < 64; ++j) local += sc[t0 + j];
    ts[tid] = local;
    __syncthreads();
    for (int off = 1; off < 256; off <<= 1) {
        int t = (tid >= off) ? ts[tid - off] : 0;
        __syncthreads();
        ts[tid] += t;
        __syncthreads();
    }
    int run = ts[tid] - local;
    for (int j = 0; j < 64; ++j) { int c = sc[t0 + j]; sc[t0 + j] = run; run += c; }
    __syncthreads();
    // rs[row] = start of row's run (key (row,0)); read before scatter mutates sc
    int row = base + tid;
    if (row < N) rs[row] = fs + sc[tid << 6];
    if (fb == 0 && tid == 0) rs[N] = E;
    __syncthreads();
    for (int i = fs + tid; i < fe; i += 256) {
        uint2 t2 = cv1[i];
        unsigned m = t2.x;
        int key = (int)((m >> 18) << 6) | (int)((m & 0x3FFFFu) >> 12);
        int pos = fs + atomicAdd(&sc[key], 1);
        cv2[pos] = make_uint2(m & 0x3FFFFu, t2.y);
    }
}

// ---------------- SpMM: wave = row, register accumulation, bf16 output, NT edge stream ----------------
__global__ void spmm_k(const int* __restrict__ rs, const uint64_t* __restrict__ cv,
                       const unsigned* __restrict__ xw, unsigned* __restrict__ aggw, int N) {
    int gw = (blockIdx.x * blockDim.x + threadIdx.x) >> 6;
    if (gw >= N) return;
    int lane = threadIdx.x & 63;
    int s = __builtin_amdgcn_readfirstlane(rs[gw]);
    int e = __builtin_amdgcn_readfirstlane(rs[gw + 1]);
    float a0 = 0.f, a1 = 0.f;
    int k = s;
    for (; k + 7 < e; k += 8) {                 // 8 independent gathers in flight
        uint64_t q0 = __builtin_nontemporal_load(cv + k);
        uint64_t q1 = __builtin_nontemporal_load(cv + k + 1);
        uint64_t q2 = __builtin_nontemporal_load(cv + k + 2);
        uint64_t q3 = __builtin_nontemporal_load(cv + k + 3);
        uint64_t q4 = __builtin_nontemporal_load(cv + k + 4);
        uint64_t q5 = __builtin_nontemporal_load(cv + k + 5);
        uint64_t q6 = __builtin_nontemporal_load(cv + k + 6);
        uint64_t q7 = __builtin_nontemporal_load(cv + k + 7);
        unsigned u0 = xw[((size_t)(unsigned)q0 << 6) + lane];
        unsigned u1 = xw[((size_t)(unsigned)q1 << 6) + lane];
        unsigned u2 = xw[((size_t)(unsigned)q2 << 6) + lane];
        unsigned u3 = xw[((size_t)(unsigned)q3 << 6) + lane];
        unsigned u4 = xw[((size_t)(unsigned)q4 << 6) + lane];
        unsigned u5 = xw[((size_t)(unsigned)q5 << 6) + lane];
        unsigned u6 = xw[((size_t)(unsigned)q6 << 6) + lane];
        unsigned u7 = xw[((size_t)(unsigned)q7 << 6) + lane];
        float v0 = __uint_as_float((unsigned)(q0 >> 32));
        float v1 = __uint_as_float((unsigned)(q1 >> 32));
        float v2 = __uint_as_float((unsigned)(q2 >> 32));
        float v3 = __uint_as_float((unsigned)(q3 >> 32));
        float v4 = __uint_as_float((unsigned)(q4 >> 32));
        float v5 = __uint_as_float((unsigned)(q5 >> 32));
        float v6 = __uint_as_float((unsigned)(q6 >> 32));
        float v7 = __uint_as_float((unsigned)(q7 >> 32));
        a0 = fmaf(v0, bf2f(u0 & 0xFFFFu), a0); a1 = fmaf(v0, bf2f(u0 >> 16), a1);
        a0 = fmaf(v1, bf2f(u1 & 0xFFFFu), a0); a1 = fmaf(v1, bf2f(u1 >> 16), a1);
        a0 = fmaf(v2, bf2f(u2 & 0xFFFFu), a0); a1 = fmaf(v2, bf2f(u2 >> 16), a1);
        a0 = fmaf(v3, bf2f(u3 & 0xFFFFu), a0); a1 = fmaf(v3, bf2f(u3 >> 16), a1);
        a0 = fmaf(v4, bf2f(u4 & 0xFFFFu), a0); a1 = fmaf(v4, bf2f(u4 >> 16), a1);
        a0 = fmaf(v5, bf2f(u5 & 0xFFFFu), a0); a1 = fmaf(v5, bf2f(u5 >> 16), a1);
        a0 = fmaf(v6, bf2f(u6 & 0xFFFFu), a0); a1 = fmaf(v6, bf2f(u6 >> 16), a1);
        a0 = fmaf(v7, bf2f(u7 & 0xFFFFu), a0); a1 = fmaf(v7, bf2f(u7 >> 16), a1);
    }
    for (; k < e; ++k) {
        uint64_t q0 = __builtin_nontemporal_load(cv + k);
        unsigned u0 = xw[((size_t)(unsigned)q0 << 6) + lane];
        float v0 = __uint_as_float((unsigned)(q0 >> 32));
        a0 = fmaf(v0, bf2f(u0 & 0xFFFFu), a0);
        a1 = fmaf(v0, bf2f(u0 >> 16), a1);
    }
    aggw[(size_t)gw * 64 + lane] = f2bf_rne(a0) | (f2bf_rne(a1) << 16);
}

// ---------------- dense via MFMA: out = relu(bf16agg @ W + b) ----------------
// block = 64 rows (4 waves x 16 rows); W^T staged in LDS as bf16, XOR-swizzled.
__global__ __launch_bounds__(256) void dense_mfma_k(const unsigned* __restrict__ aggw,
                                                    const float* __restrict__ W,
                                                    const float* __restrict__ b,
                                                    float* __restrict__ out_f,
                                                    unsigned short* __restrict__ out_us, int N) {
    __shared__ unsigned short wt[128 * 128];   // wt[c][swizzled k], bf16 of W^T
    int tid = threadIdx.x;
#pragma unroll
    for (int i = 0; i < 64; ++i) {
        int idx = tid + i * 256;
        int k = idx >> 7, c = idx & 127;
        unsigned short h = (unsigned short)f2bf_rne(W[idx]);
        wt[c * 128 + (((k >> 3) ^ (c & 15)) << 3) + (k & 7)] = h;
    }
    int lane = tid & 63;
    int wv = tid >> 6;
    int cl = lane & 15;
    int kg = lane >> 4;
    float breg[8];
#pragma unroll
    for (int ct = 0; ct < 8; ++ct) breg[ct] = b[ct * 16 + cl];
    __syncthreads();

    int base = blockIdx.x * 64 + wv * 16;
    int arow = base + cl;
    if (arow >= N) arow = N - 1;
    const uint4* arp = reinterpret_cast<const uint4*>(aggw + (size_t)arow * 64);

    f32x4 acc[8];
#pragma unroll
    for (int ct = 0; ct < 8; ++ct) acc[ct] = (f32x4){0.f, 0.f, 0.f, 0.f};

#pragma unroll
    for (int kk = 0; kk < 4; ++kk) {
        uint4 av = arp[kk * 4 + kg];
        short8 a = *reinterpret_cast<short8*>(&av);
        int u = kk * 4 + kg;
#pragma unroll
        for (int ct = 0; ct < 8; ++ct) {
            int c = ct * 16 + cl;
            uint4 bv = *reinterpret_cast<const uint4*>(&wt[c * 128 + ((u ^ (c & 15)) << 3)]);
            short8 bfr = *reinterpret_cast<short8*>(&bv);
            acc[ct] = __builtin_amdgcn_mfma_f32_16x16x32_bf16(a, bfr, acc[ct], 0, 0, 0);
        }
    }

    int orow = base + (lane >> 4) * 4;
#pragma unroll
    for (int ct = 0; ct < 8; ++ct) {
        int col = ct * 16 + cl;
#pragma unroll
        for (int i = 0; i < 4; ++i) {
            int r = orow + i;
            if (r < N) {
                float v = fmaxf(acc[ct][i] + breg[ct], 0.f);
                if (out_us) out_us[(size_t)r * 128 + col] = (unsigned short)f2bf_rne(v);
                else        out_f [(size_t)r * 128 + col] = v;
            }
        }
    }
}

extern "C" void kernel_launch(void* const* d_in, const int* in_sizes, int n_in,
                              void* d_out, int out_size, void* d_ws, size_t ws_size,
                              hipStream_t stream) {
    const int*   nid  = (const int*)d_in[0];
    const int*   erow = (const int*)d_in[1];
    const int*   ecol = (const int*)d_in[2];
    const float* eval = (const float*)d_in[3];
    const float* emb  = (const float*)d_in[4];
    const float* W1   = (const float*)d_in[5];
    const float* b1   = (const float*)d_in[6];
    const float* W2   = (const float*)d_in[7];
    const float* b2   = (const float*)d_in[8];
    int N = in_sizes[0];
    int E = in_sizes[1];
    float* out = (float*)d_out;

    int NBKT = (N + 255) >> 8;                    // buckets of 256 rows

    auto al = [](size_t x) { return (x + 255) & ~(size_t)255; };
    char* w = (char*)d_ws;
    int*      gcnt   = (int*)w;      w += al((size_t)NBKT * 4);
    int*      fstart = (int*)w;      w += al((size_t)(NBKT + 1) * 4);
    int*      gcur   = (int*)w;      w += al((size_t)NBKT * 4);
    int*      rs     = (int*)w;      w += al((size_t)(N + 1) * 4);
    // cv1 (E*8 B) aliases aggw (N*256 B): cv1 is dead after rowsort, aggw written later
    size_t big = (size_t)E * 8 > (size_t)N * 256 ? (size_t)E * 8 : (size_t)N * 256;
    uint2*    cv1    = (uint2*)w;
    unsigned* aggw   = (unsigned*)w; w += al(big);
    uint2*    cv2    = (uint2*)w;    w += al((size_t)E * 8);
    unsigned* xw     = (unsigned*)w; w += al((size_t)N * 64 * 4);   // bf16 x

    hipMemsetAsync(gcnt, 0, (size_t)NBKT * 4, stream);

    // x0 (bf16)
    gather_x0bf_k<<<(N * 64 + 255) / 256, 256, 0, stream>>>(nid, emb, xw, N);

    // CSR build: bucket-group then per-bucket (row, colbin) sort
    size_t ghistLds = (size_t)NBKT * 4;
    ghist_k<<<1024, 256, ghistLds, stream>>>(erow, gcnt, E, NBKT);
    scanB_k<<<1, 256, 0, stream>>>(gcnt, fstart, gcur, NBKT);
    size_t binLds = (size_t)BIN_TILE * 12 + (size_t)NBKT * 4 * 4;
    int binBlocks = (E + BIN_TILE - 1) / BIN_TILE;
    bin_k<<<binBlocks, BIN_THREADS, binLds, stream>>>(erow, ecol, eval, gcur, cv1, E, NBKT);
    rowsort_k<<<NBKT, 256, 0, stream>>>(fstart, cv1, cv2, rs, N, E);

    int dBlocks = (N + 63) / 64;

    // layer 1: aggw = bf16(A @ x0) ; x1(bf16) = relu(aggw@W1+b1) -> xw
    spmm_k<<<(N * 64 + 255) / 256, 256, 0, stream>>>(rs, (const uint64_t*)cv2, xw, aggw, N);
    dense_mfma_k<<<dBlocks, 256, 0, stream>>>(aggw, W1, b1, nullptr, (unsigned short*)xw, N);

    // layer 2: aggw = bf16(A @ x1) ; out(f32) = relu(aggw@W2+b2)
    spmm_k<<<(N * 64 + 255) / 256, 256, 0, stream>>>(rs, (const uint64_t*)cv2, xw, aggw, N);
    dense_mfma_k<<<dBlocks, 256, 0, stream>>>(aggw, W2, b2, out, nullptr, N);
}

// Round 10
// 720.786 us; speedup vs baseline: 1.0754x; 1.0754x over previous
//
#include <hip/hip_runtime.h>
#include <cstdint>
#include <cstddef>

#define BIN_TILE    4096
#define BIN_THREADS 512

typedef __attribute__((ext_vector_type(8))) short short8;
typedef __attribute__((ext_vector_type(4))) float f32x4;

static __device__ __forceinline__ unsigned f2bf_rne(float f) {
    unsigned u = __float_as_uint(f);
    return (u + 0x7FFFu + ((u >> 16) & 1u)) >> 16;
}
static __device__ __forceinline__ float bf2f(unsigned h) {
    return __uint_as_float(h << 16);
}

// ---------------- x0 = bf16(emb[node_ids]), float4 reads ----------------
__global__ void gather_x0bf_k(const int* __restrict__ nid, const float* __restrict__ emb,
                              uint2* __restrict__ xw2, int N) {
    int i = blockIdx.x * blockDim.x + threadIdx.x;
    int n = i >> 5;                 // 32 threads per row, 4 floats each
    if (n >= N) return;
    int l = i & 31;
    int s = nid[n];
    float4 v = *reinterpret_cast<const float4*>(emb + (size_t)s * 128 + 4 * l);
    uint2 o;
    o.x = f2bf_rne(v.x) | (f2bf_rne(v.y) << 16);
    o.y = f2bf_rne(v.z) | (f2bf_rne(v.w) << 16);
    xw2[(size_t)n * 32 + l] = o;
}

// ---------------- global bucket histogram (LDS-staged merge) ----------------
__global__ void ghist_k(const int* __restrict__ erow, int* __restrict__ gcnt, int E, int nbkt) {
    extern __shared__ int lcnt[];
    for (int i = threadIdx.x; i < nbkt; i += blockDim.x) lcnt[i] = 0;
    __syncthreads();
    for (int e = blockIdx.x * blockDim.x + threadIdx.x; e < E; e += gridDim.x * blockDim.x)
        atomicAdd(&lcnt[erow[e] >> 8], 1);
    __syncthreads();
    for (int i = threadIdx.x; i < nbkt; i += blockDim.x)
        if (lcnt[i]) atomicAdd(&gcnt[i], lcnt[i]);
}

// ---------------- single-block exclusive scan over nbkt (<=1024) buckets ----------------
__global__ void scanB_k(const int* __restrict__ gcnt, int* __restrict__ fstart,
                        int* __restrict__ gcur, int nbkt) {
    __shared__ int ts[256];
    int tid = threadIdx.x;
    int idx = tid * 4;
    int v0 = (idx + 0 < nbkt) ? gcnt[idx + 0] : 0;
    int v1 = (idx + 1 < nbkt) ? gcnt[idx + 1] : 0;
    int v2 = (idx + 2 < nbkt) ? gcnt[idx + 2] : 0;
    int v3 = (idx + 3 < nbkt) ? gcnt[idx + 3] : 0;
    int local = v0 + v1 + v2 + v3;
    ts[tid] = local;
    __syncthreads();
    for (int off = 1; off < 256; off <<= 1) {
        int t = (tid >= off) ? ts[tid - off] : 0;
        __syncthreads();
        ts[tid] += t;
        __syncthreads();
    }
    int run = ts[tid] - local;
    if (idx + 0 < nbkt) { fstart[idx + 0] = run; gcur[idx + 0] = run; } run += v0;
    if (idx + 1 < nbkt) { fstart[idx + 1] = run; gcur[idx + 1] = run; } run += v1;
    if (idx + 2 < nbkt) { fstart[idx + 2] = run; gcur[idx + 2] = run; } run += v2;
    if (idx + 3 < nbkt) { fstart[idx + 3] = run; gcur[idx + 3] = run; }
    if (tid == 255) fstart[nbkt] = ts[255];
}

// ---------------- LDS-staged binning: tile -> bucket-grouped runs, coalesced flush ----------------
__global__ __launch_bounds__(BIN_THREADS) void bin_k(const int* __restrict__ erow,
                                                     const int* __restrict__ ecol,
                                                     const float* __restrict__ eval,
                                                     int* __restrict__ gcur,
                                                     uint2* __restrict__ cv1, int E, int nbkt) {
    extern __shared__ char smem[];
    uint2*    stg  = (uint2*)smem;                          // BIN_TILE*8
    unsigned* gdst = (unsigned*)(smem + BIN_TILE * 8);      // BIN_TILE*4
    int* cnt   = (int*)(smem + BIN_TILE * 12);              // nbkt
    int* off   = cnt + nbkt;                                // nbkt
    int* gbase = off + nbkt;                                // nbkt
    int* cur   = gbase + nbkt;                              // nbkt
    __shared__ int ts[BIN_THREADS];

    int tid = threadIdx.x;
    int t0 = blockIdx.x * BIN_TILE;
    int tn = min(BIN_TILE, E - t0);

    for (int i = tid; i < nbkt; i += BIN_THREADS) cnt[i] = 0;
    __syncthreads();
    for (int i = tid; i < tn; i += BIN_THREADS)
        atomicAdd(&cnt[erow[t0 + i] >> 8], 1);
    __syncthreads();
    {   // exclusive scan of cnt -> off (2 items/thread)
        int idx = tid * 2;
        int a = (idx < nbkt) ? cnt[idx] : 0;
        int b = (idx + 1 < nbkt) ? cnt[idx + 1] : 0;
        int local = a + b;
        ts[tid] = local;
        __syncthreads();
        for (int o = 1; o < BIN_THREADS; o <<= 1) {
            int t = (tid >= o) ? ts[tid - o] : 0;
            __syncthreads();
            ts[tid] += t;
            __syncthreads();
        }
        int run = ts[tid] - local;
        if (idx < nbkt) off[idx] = run;
        if (idx + 1 < nbkt) off[idx + 1] = run + a;
    }
    __syncthreads();
    for (int b = tid; b < nbkt; b += BIN_THREADS) {
        int c = cnt[b];
        gbase[b] = c ? atomicAdd(&gcur[b], c) : 0;
        cur[b] = 0;
    }
    __syncthreads();
    for (int i = tid; i < tn; i += BIN_THREADS) {
        int r = erow[t0 + i];
        int b = r >> 8;
        unsigned meta = ((unsigned)(r & 255) << 18) | (unsigned)ecol[t0 + i];
        int s = off[b] + atomicAdd(&cur[b], 1);
        stg[s] = make_uint2(meta, __float_as_uint(eval[t0 + i]));
        gdst[s] = (unsigned)(gbase[b] + (s - off[b]));
    }
    __syncthreads();
    for (int s = tid; s < tn; s += BIN_THREADS)
        cv1[gdst[s]] = stg[s];
}

// ---------------- per-bucket row sort: bucket-grouped -> row-sorted, plus rs[] ----------------
__global__ __launch_bounds__(256) void rowsort_k(const int* __restrict__ fstart,
                                                 const uint2* __restrict__ cv1,
                                                 uint2* __restrict__ cv2,
                                                 int* __restrict__ rs, int N, int E) {
    __shared__ int cnt[256];
    __shared__ int cur[256];
    __shared__ int ts[256];
    int fb = blockIdx.x;
    int base = fb << 8;
    int tid = threadIdx.x;
    cnt[tid] = 0;
    __syncthreads();
    int fs = fstart[fb], fe = fstart[fb + 1];
    for (int i = fs + tid; i < fe; i += 256)
        atomicAdd(&cnt[cv1[i].x >> 18], 1);
    __syncthreads();
    int v = cnt[tid];
    ts[tid] = v;
    __syncthreads();
    for (int off = 1; off < 256; off <<= 1) {
        int t = (tid >= off) ? ts[tid - off] : 0;
        __syncthreads();
        ts[tid] += t;
        __syncthreads();
    }
    int start = fs + ts[tid] - v;   // this row's global start
    int row = base + tid;
    if (row < N) rs[row] = start;
    cur[tid] = start;
    if (fb == 0 && tid == 0) rs[N] = E;
    __syncthreads();
    for (int i = fs + tid; i < fe; i += 256) {
        uint2 t2 = cv1[i];
        int pos = atomicAdd(&cur[t2.x >> 18], 1);
        cv2[pos] = make_uint2(t2.x & 0x3FFFFu, t2.y);
    }
}

// ---------------- SpMM: wave = row, register accumulation, bf16 output, NT edge stream ----------------
__global__ void spmm_k(const int* __restrict__ rs, const uint64_t* __restrict__ cv,
                       const unsigned* __restrict__ xw, unsigned* __restrict__ aggw, int N) {
    int gw = (blockIdx.x * blockDim.x + threadIdx.x) >> 6;
    if (gw >= N) return;
    int lane = threadIdx.x & 63;
    int s = __builtin_amdgcn_readfirstlane(rs[gw]);
    int e = __builtin_amdgcn_readfirstlane(rs[gw + 1]);
    float a0 = 0.f, a1 = 0.f;
    int k = s;
    for (; k + 7 < e; k += 8) {                 // 8 independent gathers in flight
        uint64_t q0 = __builtin_nontemporal_load(cv + k);
        uint64_t q1 = __builtin_nontemporal_load(cv + k + 1);
        uint64_t q2 = __builtin_nontemporal_load(cv + k + 2);
        uint64_t q3 = __builtin_nontemporal_load(cv + k + 3);
        uint64_t q4 = __builtin_nontemporal_load(cv + k + 4);
        uint64_t q5 = __builtin_nontemporal_load(cv + k + 5);
        uint64_t q6 = __builtin_nontemporal_load(cv + k + 6);
        uint64_t q7 = __builtin_nontemporal_load(cv + k + 7);
        unsigned u0 = xw[((size_t)(unsigned)q0 << 6) + lane];
        unsigned u1 = xw[((size_t)(unsigned)q1 << 6) + lane];
        unsigned u2 = xw[((size_t)(unsigned)q2 << 6) + lane];
        unsigned u3 = xw[((size_t)(unsigned)q3 << 6) + lane];
        unsigned u4 = xw[((size_t)(unsigned)q4 << 6) + lane];
        unsigned u5 = xw[((size_t)(unsigned)q5 << 6) + lane];
        unsigned u6 = xw[((size_t)(unsigned)q6 << 6) + lane];
        unsigned u7 = xw[((size_t)(unsigned)q7 << 6) + lane];
        float v0 = __uint_as_float((unsigned)(q0 >> 32));
        float v1 = __uint_as_float((unsigned)(q1 >> 32));
        float v2 = __uint_as_float((unsigned)(q2 >> 32));
        float v3 = __uint_as_float((unsigned)(q3 >> 32));
        float v4 = __uint_as_float((unsigned)(q4 >> 32));
        float v5 = __uint_as_float((unsigned)(q5 >> 32));
        float v6 = __uint_as_float((unsigned)(q6 >> 32));
        float v7 = __uint_as_float((unsigned)(q7 >> 32));
        a0 = fmaf(v0, bf2f(u0 & 0xFFFFu), a0); a1 = fmaf(v0, bf2f(u0 >> 16), a1);
        a0 = fmaf(v1, bf2f(u1 & 0xFFFFu), a0); a1 = fmaf(v1, bf2f(u1 >> 16), a1);
        a0 = fmaf(v2, bf2f(u2 & 0xFFFFu), a0); a1 = fmaf(v2, bf2f(u2 >> 16), a1);
        a0 = fmaf(v3, bf2f(u3 & 0xFFFFu), a0); a1 = fmaf(v3, bf2f(u3 >> 16), a1);
        a0 = fmaf(v4, bf2f(u4 & 0xFFFFu), a0); a1 = fmaf(v4, bf2f(u4 >> 16), a1);
        a0 = fmaf(v5, bf2f(u5 & 0xFFFFu), a0); a1 = fmaf(v5, bf2f(u5 >> 16), a1);
        a0 = fmaf(v6, bf2f(u6 & 0xFFFFu), a0); a1 = fmaf(v6, bf2f(u6 >> 16), a1);
        a0 = fmaf(v7, bf2f(u7 & 0xFFFFu), a0); a1 = fmaf(v7, bf2f(u7 >> 16), a1);
    }
    for (; k < e; ++k) {
        uint64_t q0 = __builtin_nontemporal_load(cv + k);
        unsigned u0 = xw[((size_t)(unsigned)q0 << 6) + lane];
        float v0 = __uint_as_float((unsigned)(q0 >> 32));
        a0 = fmaf(v0, bf2f(u0 & 0xFFFFu), a0);
        a1 = fmaf(v0, bf2f(u0 >> 16), a1);
    }
    aggw[(size_t)gw * 64 + lane] = f2bf_rne(a0) | (f2bf_rne(a1) << 16);
}

// ---------------- dense via MFMA: out = relu(bf16agg @ W + b) ----------------
// block = 64 rows (4 waves x 16 rows); W^T staged in LDS as bf16, XOR-swizzled.
__global__ __launch_bounds__(256) void dense_mfma_k(const unsigned* __restrict__ aggw,
                                                    const float* __restrict__ W,
                                                    const float* __restrict__ b,
                                                    float* __restrict__ out_f,
                                                    unsigned short* __restrict__ out_us, int N) {
    __shared__ unsigned short wt[128 * 128];   // wt[c][swizzled k], bf16 of W^T
    int tid = threadIdx.x;
#pragma unroll
    for (int i = 0; i < 64; ++i) {
        int idx = tid + i * 256;
        int k = idx >> 7, c = idx & 127;
        unsigned short h = (unsigned short)f2bf_rne(W[idx]);
        wt[c * 128 + (((k >> 3) ^ (c & 15)) << 3) + (k & 7)] = h;
    }
    int lane = tid & 63;
    int wv = tid >> 6;
    int cl = lane & 15;
    int kg = lane >> 4;
    float breg[8];
#pragma unroll
    for (int ct = 0; ct < 8; ++ct) breg[ct] = b[ct * 16 + cl];
    __syncthreads();

    int base = blockIdx.x * 64 + wv * 16;
    int arow = base + cl;
    if (arow >= N) arow = N - 1;
    const uint4* arp = reinterpret_cast<const uint4*>(aggw + (size_t)arow * 64);

    f32x4 acc[8];
#pragma unroll
    for (int ct = 0; ct < 8; ++ct) acc[ct] = (f32x4){0.f, 0.f, 0.f, 0.f};

#pragma unroll
    for (int kk = 0; kk < 4; ++kk) {
        uint4 av = arp[kk * 4 + kg];
        short8 a = *reinterpret_cast<short8*>(&av);
        int u = kk * 4 + kg;
#pragma unroll
        for (int ct = 0; ct < 8; ++ct) {
            int c = ct * 16 + cl;
            uint4 bv = *reinterpret_cast<const uint4*>(&wt[c * 128 + ((u ^ (c & 15)) << 3)]);
            short8 bfr = *reinterpret_cast<short8*>(&bv);
            acc[ct] = __builtin_amdgcn_mfma_f32_16x16x32_bf16(a, bfr, acc[ct], 0, 0, 0);
        }
    }

    int orow = base + (lane >> 4) * 4;
#pragma unroll
    for (int ct = 0; ct < 8; ++ct) {
        int col = ct * 16 + cl;
#pragma unroll
        for (int i = 0; i < 4; ++i) {
            int r = orow + i;
            if (r < N) {
                float v = fmaxf(acc[ct][i] + breg[ct], 0.f);
                if (out_us) out_us[(size_t)r * 128 + col] = (unsigned short)f2bf_rne(v);
                else        out_f [(size_t)r * 128 + col] = v;
            }
        }
    }
}

extern "C" void kernel_launch(void* const* d_in, const int* in_sizes, int n_in,
                              void* d_out, int out_size, void* d_ws, size_t ws_size,
                              hipStream_t stream) {
    const int*   nid  = (const int*)d_in[0];
    const int*   erow = (const int*)d_in[1];
    const int*   ecol = (const int*)d_in[2];
    const float* eval = (const float*)d_in[3];
    const float* emb  = (const float*)d_in[4];
    const float* W1   = (const float*)d_in[5];
    const float* b1   = (const float*)d_in[6];
    const float* W2   = (const float*)d_in[7];
    const float* b2   = (const float*)d_in[8];
    int N = in_sizes[0];
    int E = in_sizes[1];
    float* out = (float*)d_out;

    int NBKT = (N + 255) >> 8;                    // buckets of 256 rows

    auto al = [](size_t x) { return (x + 255) & ~(size_t)255; };
    char* w = (char*)d_ws;
    int*      gcnt   = (int*)w;      w += al((size_t)NBKT * 4);
    int*      fstart = (int*)w;      w += al((size_t)(NBKT + 1) * 4);
    int*      gcur   = (int*)w;      w += al((size_t)NBKT * 4);
    int*      rs     = (int*)w;      w += al((size_t)(N + 1) * 4);
    // cv1 (E*8 B) aliases aggw (N*256 B): cv1 is dead after rowsort, aggw written later
    size_t big = (size_t)E * 8 > (size_t)N * 256 ? (size_t)E * 8 : (size_t)N * 256;
    uint2*    cv1    = (uint2*)w;
    unsigned* aggw   = (unsigned*)w; w += al(big);
    uint2*    cv2    = (uint2*)w;    w += al((size_t)E * 8);
    unsigned* xw     = (unsigned*)w; w += al((size_t)N * 64 * 4);   // bf16 x

    hipMemsetAsync(gcnt, 0, (size_t)NBKT * 4, stream);

    // x0 (bf16)
    gather_x0bf_k<<<(N * 32 + 255) / 256, 256, 0, stream>>>(nid, emb, (uint2*)xw, N);

    // CSR build: bucket-group then per-bucket row sort
    size_t ghistLds = (size_t)NBKT * 4;
    ghist_k<<<1024, 256, ghistLds, stream>>>(erow, gcnt, E, NBKT);
    scanB_k<<<1, 256, 0, stream>>>(gcnt, fstart, gcur, NBKT);
    size_t binLds = (size_t)BIN_TILE * 12 + (size_t)NBKT * 4 * 4;
    int binBlocks = (E + BIN_TILE - 1) / BIN_TILE;
    bin_k<<<binBlocks, BIN_THREADS, binLds, stream>>>(erow, ecol, eval, gcur, cv1, E, NBKT);
    rowsort_k<<<NBKT, 256, 0, stream>>>(fstart, cv1, cv2, rs, N, E);

    int dBlocks = (N + 63) / 64;

    // layer 1: aggw = bf16(A @ x0) ; x1(bf16) = relu(aggw@W1+b1) -> xw
    spmm_k<<<(N * 64 + 255) / 256, 256, 0, stream>>>(rs, (const uint64_t*)cv2, xw, aggw, N);
    dense_mfma_k<<<dBlocks, 256, 0, stream>>>(aggw, W1, b1, nullptr, (unsigned short*)xw, N);

    // layer 2: aggw = bf16(A @ x1) ; out(f32) = relu(aggw@W2+b2)
    spmm_k<<<(N * 64 + 255) / 256, 256, 0, stream>>>(rs, (const uint64_t*)cv2, xw, aggw, N);
    dense_mfma_k<<<dBlocks, 256, 0, stream>>>(aggw, W2, b2, out, nullptr, N);
}

// Round 11
// 705.541 us; speedup vs baseline: 1.0987x; 1.0216x over previous
//
#include <hip/hip_runtime.h>
#include <cstdint>
#include <cstddef>

#define BIN_TILE    4096
#define BIN_THREADS 512

typedef __attribute__((ext_vector_type(8))) short short8;
typedef __attribute__((ext_vector_type(4))) float f32x4;

static __device__ __forceinline__ unsigned f2bf_rne(float f) {
    unsigned u = __float_as_uint(f);
    return (u + 0x7FFFu + ((u >> 16) & 1u)) >> 16;
}
static __device__ __forceinline__ float bf2f(unsigned h) {
    return __uint_as_float(h << 16);
}

// ---------------- x0 = bf16(emb[node_ids]), float4 reads; also zeroes gcnt ----------------
__global__ void gather_x0bf_k(const int* __restrict__ nid, const float* __restrict__ emb,
                              uint2* __restrict__ xw2, int* __restrict__ gcnt, int nbkt, int N) {
    int i = blockIdx.x * blockDim.x + threadIdx.x;
    if (i < nbkt) gcnt[i] = 0;
    int n = i >> 5;                 // 32 threads per row, 4 floats each
    if (n >= N) return;
    int l = i & 31;
    int s = nid[n];
    float4 v = *reinterpret_cast<const float4*>(emb + (size_t)s * 128 + 4 * l);
    uint2 o;
    o.x = f2bf_rne(v.x) | (f2bf_rne(v.y) << 16);
    o.y = f2bf_rne(v.z) | (f2bf_rne(v.w) << 16);
    xw2[(size_t)n * 32 + l] = o;
}

// ---------------- W1,W2 -> bf16 in the swizzled wt-LDS layout (once) ----------------
__global__ void wbf_k(const float* __restrict__ W1, const float* __restrict__ W2,
                      unsigned short* __restrict__ wswz) {
    int idx = blockIdx.x * blockDim.x + threadIdx.x;   // 0..32767
    int layer = idx >> 14;
    int e = idx & 16383;
    int k = e >> 7, c = e & 127;
    float f = layer ? W2[e] : W1[e];
    wswz[(layer << 14) + c * 128 + (((k >> 3) ^ (c & 15)) << 3) + (k & 7)] =
        (unsigned short)f2bf_rne(f);
}

// ---------------- global bucket histogram (LDS-staged merge) ----------------
__global__ void ghist_k(const int* __restrict__ erow, int* __restrict__ gcnt, int E, int nbkt) {
    extern __shared__ int lcnt[];
    for (int i = threadIdx.x; i < nbkt; i += blockDim.x) lcnt[i] = 0;
    __syncthreads();
    for (int e = blockIdx.x * blockDim.x + threadIdx.x; e < E; e += gridDim.x * blockDim.x)
        atomicAdd(&lcnt[erow[e] >> 8], 1);
    __syncthreads();
    for (int i = threadIdx.x; i < nbkt; i += blockDim.x)
        if (lcnt[i]) atomicAdd(&gcnt[i], lcnt[i]);
}

// ---------------- single-block exclusive scan over nbkt (<=1024) buckets ----------------
__global__ void scanB_k(const int* __restrict__ gcnt, int* __restrict__ fstart,
                        int* __restrict__ gcur, int nbkt) {
    __shared__ int ts[256];
    int tid = threadIdx.x;
    int idx = tid * 4;
    int v0 = (idx + 0 < nbkt) ? gcnt[idx + 0] : 0;
    int v1 = (idx + 1 < nbkt) ? gcnt[idx + 1] : 0;
    int v2 = (idx + 2 < nbkt) ? gcnt[idx + 2] : 0;
    int v3 = (idx + 3 < nbkt) ? gcnt[idx + 3] : 0;
    int local = v0 + v1 + v2 + v3;
    ts[tid] = local;
    __syncthreads();
    for (int off = 1; off < 256; off <<= 1) {
        int t = (tid >= off) ? ts[tid - off] : 0;
        __syncthreads();
        ts[tid] += t;
        __syncthreads();
    }
    int run = ts[tid] - local;
    if (idx + 0 < nbkt) { fstart[idx + 0] = run; gcur[idx + 0] = run; } run += v0;
    if (idx + 1 < nbkt) { fstart[idx + 1] = run; gcur[idx + 1] = run; } run += v1;
    if (idx + 2 < nbkt) { fstart[idx + 2] = run; gcur[idx + 2] = run; } run += v2;
    if (idx + 3 < nbkt) { fstart[idx + 3] = run; gcur[idx + 3] = run; }
    if (tid == 255) fstart[nbkt] = ts[255];
}

// ---------------- LDS-staged binning: tile -> bucket-grouped runs, coalesced flush ----------------
__global__ __launch_bounds__(BIN_THREADS) void bin_k(const int* __restrict__ erow,
                                                     const int* __restrict__ ecol,
                                                     const float* __restrict__ eval,
                                                     int* __restrict__ gcur,
                                                     uint2* __restrict__ cv1, int E, int nbkt) {
    extern __shared__ char smem[];
    uint2*    stg  = (uint2*)smem;                          // BIN_TILE*8
    unsigned* gdst = (unsigned*)(smem + BIN_TILE * 8);      // BIN_TILE*4
    int* cnt   = (int*)(smem + BIN_TILE * 12);              // nbkt
    int* off   = cnt + nbkt;                                // nbkt
    int* gbase = off + nbkt;                                // nbkt
    int* cur   = gbase + nbkt;                              // nbkt
    __shared__ int ts[BIN_THREADS];

    int tid = threadIdx.x;
    int t0 = blockIdx.x * BIN_TILE;
    int tn = min(BIN_TILE, E - t0);

    for (int i = tid; i < nbkt; i += BIN_THREADS) cnt[i] = 0;
    __syncthreads();
    for (int i = tid; i < tn; i += BIN_THREADS)
        atomicAdd(&cnt[erow[t0 + i] >> 8], 1);
    __syncthreads();
    {   // exclusive scan of cnt -> off (2 items/thread)
        int idx = tid * 2;
        int a = (idx < nbkt) ? cnt[idx] : 0;
        int b = (idx + 1 < nbkt) ? cnt[idx + 1] : 0;
        int local = a + b;
        ts[tid] = local;
        __syncthreads();
        for (int o = 1; o < BIN_THREADS; o <<= 1) {
            int t = (tid >= o) ? ts[tid - o] : 0;
            __syncthreads();
            ts[tid] += t;
            __syncthreads();
        }
        int run = ts[tid] - local;
        if (idx < nbkt) off[idx] = run;
        if (idx + 1 < nbkt) off[idx + 1] = run + a;
    }
    __syncthreads();
    for (int b = tid; b < nbkt; b += BIN_THREADS) {
        int c = cnt[b];
        gbase[b] = c ? atomicAdd(&gcur[b], c) : 0;
        cur[b] = 0;
    }
    __syncthreads();
    for (int i = tid; i < tn; i += BIN_THREADS) {
        int r = erow[t0 + i];
        int b = r >> 8;
        unsigned meta = ((unsigned)(r & 255) << 18) | (unsigned)ecol[t0 + i];
        int s = off[b] + atomicAdd(&cur[b], 1);
        stg[s] = make_uint2(meta, __float_as_uint(eval[t0 + i]));
        gdst[s] = (unsigned)(gbase[b] + (s - off[b]));
    }
    __syncthreads();
    for (int s = tid; s < tn; s += BIN_THREADS)
        cv1[gdst[s]] = stg[s];
}

// ---------------- per-bucket row sort: bucket-grouped -> row-sorted, plus rs[] ----------------
__global__ __launch_bounds__(256) void rowsort_k(const int* __restrict__ fstart,
                                                 const uint2* __restrict__ cv1,
                                                 uint2* __restrict__ cv2,
                                                 int* __restrict__ rs, int N, int E) {
    __shared__ int cnt[256];
    __shared__ int cur[256];
    __shared__ int ts[256];
    int fb = blockIdx.x;
    int base = fb << 8;
    int tid = threadIdx.x;
    cnt[tid] = 0;
    __syncthreads();
    int fs = fstart[fb], fe = fstart[fb + 1];
    for (int i = fs + tid; i < fe; i += 256)
        atomicAdd(&cnt[cv1[i].x >> 18], 1);
    __syncthreads();
    int v = cnt[tid];
    ts[tid] = v;
    __syncthreads();
    for (int off = 1; off < 256; off <<= 1) {
        int t = (tid >= off) ? ts[tid - off] : 0;
        __syncthreads();
        ts[tid] += t;
        __syncthreads();
    }
    int start = fs + ts[tid] - v;   // this row's global start
    int row = base + tid;
    if (row < N) rs[row] = start;
    cur[tid] = start;
    if (fb == 0 && tid == 0) rs[N] = E;
    __syncthreads();
    for (int i = fs + tid; i < fe; i += 256) {
        uint2 t2 = cv1[i];
        int pos = atomicAdd(&cur[t2.x >> 18], 1);
        cv2[pos] = make_uint2(t2.x & 0x3FFFFu, t2.y);
    }
}

// ---------------- SpMM: wave = row, register accumulation, bf16 output, NT edge stream ----------------
__global__ void spmm_k(const int* __restrict__ rs, const uint64_t* __restrict__ cv,
                       const unsigned* __restrict__ xw, unsigned* __restrict__ aggw, int N) {
    int gw = (blockIdx.x * blockDim.x + threadIdx.x) >> 6;
    if (gw >= N) return;
    int lane = threadIdx.x & 63;
    int s = __builtin_amdgcn_readfirstlane(rs[gw]);
    int e = __builtin_amdgcn_readfirstlane(rs[gw + 1]);
    float a0 = 0.f, a1 = 0.f;
    int k = s;
    for (; k + 7 < e; k += 8) {                 // 8 independent gathers in flight
        uint64_t q0 = __builtin_nontemporal_load(cv + k);
        uint64_t q1 = __builtin_nontemporal_load(cv + k + 1);
        uint64_t q2 = __builtin_nontemporal_load(cv + k + 2);
        uint64_t q3 = __builtin_nontemporal_load(cv + k + 3);
        uint64_t q4 = __builtin_nontemporal_load(cv + k + 4);
        uint64_t q5 = __builtin_nontemporal_load(cv + k + 5);
        uint64_t q6 = __builtin_nontemporal_load(cv + k + 6);
        uint64_t q7 = __builtin_nontemporal_load(cv + k + 7);
        unsigned u0 = xw[((size_t)(unsigned)q0 << 6) + lane];
        unsigned u1 = xw[((size_t)(unsigned)q1 << 6) + lane];
        unsigned u2 = xw[((size_t)(unsigned)q2 << 6) + lane];
        unsigned u3 = xw[((size_t)(unsigned)q3 << 6) + lane];
        unsigned u4 = xw[((size_t)(unsigned)q4 << 6) + lane];
        unsigned u5 = xw[((size_t)(unsigned)q5 << 6) + lane];
        unsigned u6 = xw[((size_t)(unsigned)q6 << 6) + lane];
        unsigned u7 = xw[((size_t)(unsigned)q7 << 6) + lane];
        float v0 = __uint_as_float((unsigned)(q0 >> 32));
        float v1 = __uint_as_float((unsigned)(q1 >> 32));
        float v2 = __uint_as_float((unsigned)(q2 >> 32));
        float v3 = __uint_as_float((unsigned)(q3 >> 32));
        float v4 = __uint_as_float((unsigned)(q4 >> 32));
        float v5 = __uint_as_float((unsigned)(q5 >> 32));
        float v6 = __uint_as_float((unsigned)(q6 >> 32));
        float v7 = __uint_as_float((unsigned)(q7 >> 32));
        a0 = fmaf(v0, bf2f(u0 & 0xFFFFu), a0); a1 = fmaf(v0, bf2f(u0 >> 16), a1);
        a0 = fmaf(v1, bf2f(u1 & 0xFFFFu), a0); a1 = fmaf(v1, bf2f(u1 >> 16), a1);
        a0 = fmaf(v2, bf2f(u2 & 0xFFFFu), a0); a1 = fmaf(v2, bf2f(u2 >> 16), a1);
        a0 = fmaf(v3, bf2f(u3 & 0xFFFFu), a0); a1 = fmaf(v3, bf2f(u3 >> 16), a1);
        a0 = fmaf(v4, bf2f(u4 & 0xFFFFu), a0); a1 = fmaf(v4, bf2f(u4 >> 16), a1);
        a0 = fmaf(v5, bf2f(u5 & 0xFFFFu), a0); a1 = fmaf(v5, bf2f(u5 >> 16), a1);
        a0 = fmaf(v6, bf2f(u6 & 0xFFFFu), a0); a1 = fmaf(v6, bf2f(u6 >> 16), a1);
        a0 = fmaf(v7, bf2f(u7 & 0xFFFFu), a0); a1 = fmaf(v7, bf2f(u7 >> 16), a1);
    }
    for (; k < e; ++k) {
        uint64_t q0 = __builtin_nontemporal_load(cv + k);
        unsigned u0 = xw[((size_t)(unsigned)q0 << 6) + lane];
        float v0 = __uint_as_float((unsigned)(q0 >> 32));
        a0 = fmaf(v0, bf2f(u0 & 0xFFFFu), a0);
        a1 = fmaf(v0, bf2f(u0 >> 16), a1);
    }
    aggw[(size_t)gw * 64 + lane] = f2bf_rne(a0) | (f2bf_rne(a1) << 16);
}

// ---------------- dense via MFMA: out = relu(bf16agg @ W + b) ----------------
// block = 64 rows (4 waves x 16 rows); W pre-swizzled bf16, straight 32KB copy into LDS.
__global__ __launch_bounds__(256) void dense_mfma_k(const unsigned* __restrict__ aggw,
                                                    const unsigned short* __restrict__ wswz,
                                                    const float* __restrict__ b,
                                                    float* __restrict__ out_f,
                                                    unsigned short* __restrict__ out_us, int N) {
    __shared__ unsigned short wt[128 * 128];   // wt[c][swizzled k], bf16 of W^T
    int tid = threadIdx.x;
    {
        const uint4* src = reinterpret_cast<const uint4*>(wswz);
        uint4* dst = reinterpret_cast<uint4*>(wt);
#pragma unroll
        for (int i = 0; i < 8; ++i)
            dst[tid + i * 256] = src[tid + i * 256];
    }
    int lane = tid & 63;
    int wv = tid >> 6;
    int cl = lane & 15;
    int kg = lane >> 4;
    float breg[8];
#pragma unroll
    for (int ct = 0; ct < 8; ++ct) breg[ct] = b[ct * 16 + cl];
    __syncthreads();

    int base = blockIdx.x * 64 + wv * 16;
    int arow = base + cl;
    if (arow >= N) arow = N - 1;
    const uint4* arp = reinterpret_cast<const uint4*>(aggw + (size_t)arow * 64);

    f32x4 acc[8];
#pragma unroll
    for (int ct = 0; ct < 8; ++ct) acc[ct] = (f32x4){0.f, 0.f, 0.f, 0.f};

#pragma unroll
    for (int kk = 0; kk < 4; ++kk) {
        uint4 av = arp[kk * 4 + kg];
        short8 a = *reinterpret_cast<short8*>(&av);
        int u = kk * 4 + kg;
#pragma unroll
        for (int ct = 0; ct < 8; ++ct) {
            int c = ct * 16 + cl;
            uint4 bv = *reinterpret_cast<const uint4*>(&wt[c * 128 + ((u ^ (c & 15)) << 3)]);
            short8 bfr = *reinterpret_cast<short8*>(&bv);
            acc[ct] = __builtin_amdgcn_mfma_f32_16x16x32_bf16(a, bfr, acc[ct], 0, 0, 0);
        }
    }

    int orow = base + (lane >> 4) * 4;
#pragma unroll
    for (int ct = 0; ct < 8; ++ct) {
        int col = ct * 16 + cl;
#pragma unroll
        for (int i = 0; i < 4; ++i) {
            int r = orow + i;
            if (r < N) {
                float v = fmaxf(acc[ct][i] + breg[ct], 0.f);
                if (out_us) out_us[(size_t)r * 128 + col] = (unsigned short)f2bf_rne(v);
                else        out_f [(size_t)r * 128 + col] = v;
            }
        }
    }
}

extern "C" void kernel_launch(void* const* d_in, const int* in_sizes, int n_in,
                              void* d_out, int out_size, void* d_ws, size_t ws_size,
                              hipStream_t stream) {
    const int*   nid  = (const int*)d_in[0];
    const int*   erow = (const int*)d_in[1];
    const int*   ecol = (const int*)d_in[2];
    const float* eval = (const float*)d_in[3];
    const float* emb  = (const float*)d_in[4];
    const float* W1   = (const float*)d_in[5];
    const float* b1   = (const float*)d_in[6];
    const float* W2   = (const float*)d_in[7];
    const float* b2   = (const float*)d_in[8];
    int N = in_sizes[0];
    int E = in_sizes[1];
    float* out = (float*)d_out;

    int NBKT = (N + 255) >> 8;                    // buckets of 256 rows

    auto al = [](size_t x) { return (x + 255) & ~(size_t)255; };
    char* w = (char*)d_ws;
    int*      gcnt   = (int*)w;      w += al((size_t)NBKT * 4);
    int*      fstart = (int*)w;      w += al((size_t)(NBKT + 1) * 4);
    int*      gcur   = (int*)w;      w += al((size_t)NBKT * 4);
    int*      rs     = (int*)w;      w += al((size_t)(N + 1) * 4);
    unsigned short* wswz = (unsigned short*)w; w += al((size_t)32768 * 2);
    // cv1 (E*8 B) aliases aggw (N*256 B): cv1 is dead after rowsort, aggw written later
    size_t big = (size_t)E * 8 > (size_t)N * 256 ? (size_t)E * 8 : (size_t)N * 256;
    uint2*    cv1    = (uint2*)w;
    unsigned* aggw   = (unsigned*)w; w += al(big);
    uint2*    cv2    = (uint2*)w;    w += al((size_t)E * 8);
    unsigned* xw     = (unsigned*)w; w += al((size_t)N * 64 * 4);   // bf16 x

    // x0 (bf16) + gcnt zero-init
    gather_x0bf_k<<<(N * 32 + 255) / 256, 256, 0, stream>>>(nid, emb, (uint2*)xw, gcnt, NBKT, N);

    // W -> bf16, pre-swizzled to the wt-LDS layout
    wbf_k<<<128, 256, 0, stream>>>(W1, W2, wswz);

    // CSR build: bucket-group then per-bucket row sort
    size_t ghistLds = (size_t)NBKT * 4;
    ghist_k<<<1024, 256, ghistLds, stream>>>(erow, gcnt, E, NBKT);
    scanB_k<<<1, 256, 0, stream>>>(gcnt, fstart, gcur, NBKT);
    size_t binLds = (size_t)BIN_TILE * 12 + (size_t)NBKT * 4 * 4;
    int binBlocks = (E + BIN_TILE - 1) / BIN_TILE;
    bin_k<<<binBlocks, BIN_THREADS, binLds, stream>>>(erow, ecol, eval, gcur, cv1, E, NBKT);
    rowsort_k<<<NBKT, 256, 0, stream>>>(fstart, cv1, cv2, rs, N, E);

    int dBlocks = (N + 63) / 64;

    // layer 1: aggw = bf16(A @ x0) ; x1(bf16) = relu(aggw@W1+b1) -> xw
    spmm_k<<<(N * 64 + 255) / 256, 256, 0, stream>>>(rs, (const uint64_t*)cv2, xw, aggw, N);
    dense_mfma_k<<<dBlocks, 256, 0, stream>>>(aggw, wswz, b1, nullptr, (unsigned short*)xw, N);

    // layer 2: aggw = bf16(A @ x1) ; out(f32) = relu(aggw@W2+b2)
    spmm_k<<<(N * 64 + 255) / 256, 256, 0, stream>>>(rs, (const uint64_t*)cv2, xw, aggw, N);
    dense_mfma_k<<<dBlocks, 256, 0, stream>>>(aggw, wswz + 16384, b2, out, nullptr, N);
}